// Round 7
// baseline (14592.097 us; speedup 1.0000x reference)
//
#include <hip/hip_runtime.h>
#include <math.h>

#define T_LEN 4096
#define HID   1024
#define G4    4096
#define KTAG  50
#define KPAD  64
#define START_TAG 48
#define END_TAG   49

// ---------------- workspace layout (float-element offsets) ----------------
#define XG_OFF     ((size_t)0)                        // [2][T][4096] f32
#define XG_SZ      ((size_t)2*T_LEN*G4)
#define HOUT_OFF   (XG_OFF + XG_SZ)                   // [2][T][1024] f32
#define HOUT_SZ    ((size_t)2*T_LEN*HID)
#define WT_OFF     (HOUT_OFF + HOUT_SZ)               // [2048][64] f32
#define WT_SZ      ((size_t)2*HID*KPAD)
#define FEATS_OFF  (WT_OFF + WT_SZ)                   // [T][64] f32
#define FEATS_SZ   ((size_t)T_LEN*KPAD)
#define BP_OFF     (FEATS_OFF + FEATS_SZ)             // [T][64] i32
#define BP_SZ      ((size_t)T_LEN*KPAD)
#define MMAP_OFF   (BP_OFF + BP_SZ)                   // [64][64] i32
#define MMAP_SZ    ((size_t)64*64)
#define ENTRY_OFF  (MMAP_OFF + MMAP_SZ)               // [64] i32
#define BEST_OFF   (ENTRY_OFF + 64)                   // [1] i32
// seq-fused h transport: [2 slots][2 dirs][1024] u64 (32 KB), 8B-aligned
#define HSEQ_OFF   (((BEST_OFF + 1) + 15) & ~(size_t)15)
#define HSEQ_SZ    ((size_t)8192)                     // in floats (4096 u64)
#define WS_NEEDED  (((HSEQ_OFF + HSEQ_SZ) * 4))

// =========================================================================
// 1) xg[d][t][r] = sum_h X[t][h]*W_ih[d][r][h] + b_ih[r] + b_hh[r]
// =========================================================================
__global__ __launch_bounds__(256, 2) void gemm_xg(
    const float* __restrict__ X, const float* __restrict__ Wf, const float* __restrict__ Wb,
    const float* __restrict__ bihf, const float* __restrict__ bhhf,
    const float* __restrict__ bihb, const float* __restrict__ bhhb,
    float* __restrict__ xg)
{
  const int d  = blockIdx.z;
  const float* __restrict__ W = d ? Wb : Wf;
  const int r0 = blockIdx.x * 64;
  const int t0 = blockIdx.y * 64;
  __shared__ float Xs[16][68];
  __shared__ float Ws[16][68];
  const int tid = threadIdx.x;
  const int tx = tid & 15, ty = tid >> 4;
  const int srow = tid >> 2, skq = (tid & 3) * 4;

  float acc[4][4];
#pragma unroll
  for (int i = 0; i < 4; ++i)
#pragma unroll
    for (int j = 0; j < 4; ++j) acc[i][j] = 0.f;

#pragma unroll 1
  for (int k0 = 0; k0 < HID; k0 += 16) {
    const float4 xv = *(const float4*)&X[(size_t)(t0 + srow) * HID + k0 + skq];
    const float4 wv = *(const float4*)&W[(size_t)(r0 + srow) * HID + k0 + skq];
    __syncthreads();
    Xs[skq + 0][srow] = xv.x; Xs[skq + 1][srow] = xv.y; Xs[skq + 2][srow] = xv.z; Xs[skq + 3][srow] = xv.w;
    Ws[skq + 0][srow] = wv.x; Ws[skq + 1][srow] = wv.y; Ws[skq + 2][srow] = wv.z; Ws[skq + 3][srow] = wv.w;
    __syncthreads();
#pragma unroll
    for (int kk = 0; kk < 16; ++kk) {
      const float4 av = *(const float4*)&Xs[kk][ty * 4];
      const float4 bv = *(const float4*)&Ws[kk][tx * 4];
      acc[0][0] += av.x * bv.x; acc[0][1] += av.x * bv.y; acc[0][2] += av.x * bv.z; acc[0][3] += av.x * bv.w;
      acc[1][0] += av.y * bv.x; acc[1][1] += av.y * bv.y; acc[1][2] += av.y * bv.z; acc[1][3] += av.y * bv.w;
      acc[2][0] += av.z * bv.x; acc[2][1] += av.z * bv.y; acc[2][2] += av.z * bv.z; acc[2][3] += av.z * bv.w;
      acc[3][0] += av.w * bv.x; acc[3][1] += av.w * bv.y; acc[3][2] += av.w * bv.z; acc[3][3] += av.w * bv.w;
    }
  }
  const float* __restrict__ b1 = d ? bihb : bihf;
  const float* __restrict__ b2 = d ? bhhb : bhhf;
  float bias[4];
#pragma unroll
  for (int j = 0; j < 4; ++j) bias[j] = b1[r0 + tx * 4 + j] + b2[r0 + tx * 4 + j];
#pragma unroll
  for (int i = 0; i < 4; ++i) {
    float4 v;
    v.x = acc[i][0] + bias[0]; v.y = acc[i][1] + bias[1];
    v.z = acc[i][2] + bias[2]; v.w = acc[i][3] + bias[3];
    *(float4*)&xg[((size_t)d * T_LEN + t0 + ty * 4 + i) * G4 + r0 + tx * 4] = v;
  }
}

// =========================================================================
// 2) Persistent bidirectional LSTM recurrence.
//    Round 7: (a) GEMV reads switched to ds_read_b64 with lane-rotated
//    block order (bb=(j+ln)&15): word addr = ln*32+2*bb -> each bank hit
//    by exactly 2 of 32 distinct addrs (2-way = free, m136), upper lane
//    group broadcasts. Kills round 6's 1.5e8 4-way b128 conflicts (a
//    contiguous-float4-per-chunk read is PROVABLY >=4-way: chunk base
//    = 0 mod 32 banks, only 8 quad choices). Weights reordered to match.
//    (b) Staggered double-sample poll: second load-pair in flight while
//    checking the first -> detect lag ~1 RT instead of ~1.5 RT.
//    (c) Packet store issued before hout store.
//    Transport unchanged: u64 {seq,f32} packets, depth-2 ring, AGENT-scope
//    relaxed atomics, one barrier/step, double-buffered hs.
// =========================================================================
__global__ __launch_bounds__(512, 1) void lstm_rec(
    const float* __restrict__ xg, const float* __restrict__ whhf,
    const float* __restrict__ whhb, float* __restrict__ hout,
    unsigned long long* __restrict__ hseq)
{
  const int g = blockIdx.x;
  const int d = g >> 6;
  const int s = g & 63;
  const float* __restrict__ whh = d ? whhb : whhf;
  const int tid = threadIdx.x;
  const int ln   = tid & 31;    // lane within h-group; covers cols [ln*32, ln*32+32)
  const int gidx = tid >> 5;    // h-slot 0..15 within slice
  const int hidx = (s << 4) + gidx;   // global h index 0..1023

  // 128 weight regs: 4 gates x 32 cols, block-rotated to match the b64
  // GEMV read order: w[gt][2j+i] = W[gt_row][ln*32 + 2*((j+ln)&15) + i]
  float w[4][32];
#pragma unroll
  for (int gt = 0; gt < 4; ++gt) {
    const float* wr = whh + ((size_t)(gt << 10) + hidx) * HID + (ln << 5);
#pragma unroll
    for (int j = 0; j < 16; ++j) {
      const int bb = (j + ln) & 15;
      const float2 v = *(const float2*)&wr[bb << 1];
      w[gt][2 * j + 0] = v.x; w[gt][2 * j + 1] = v.y;
    }
  }

  __shared__ float hs[2][1024];   // double-buffered h staging
  __shared__ int   abortf[1];
  if (tid == 0) abortf[0] = 0;
  float creg = 0.f;               // cell state (group leaders only)
  __syncthreads();

  const float* __restrict__ xgd = xg + (size_t)d * T_LEN * G4;

  // xg prefetch (depth 1 ahead), leaders only: 4 gate terms for this h
  float xc0 = 0.f, xc1 = 0.f, xc2 = 0.f, xc3 = 0.f;
  if (ln == 0) {
    const int tf = d ? (T_LEN - 1) : 0;
    const float* xr = xgd + (size_t)tf * G4 + hidx;
    xc0 = xr[0]; xc1 = xr[HID]; xc2 = xr[2 * HID]; xc3 = xr[3 * HID];
  }

#pragma unroll 1
  for (int it = 0; it < T_LEN; ++it) {
    const int t = d ? (T_LEN - 1 - it) : it;
    float xn0 = 0.f, xn1 = 0.f, xn2 = 0.f, xn3 = 0.f;
    if (ln == 0 && it + 1 < T_LEN) {   // issue next step's xg loads NOW
      const int tn = d ? (T_LEN - 2 - it) : (it + 1);
      const float* xr = xgd + (size_t)tn * G4 + hidx;
      xn0 = xr[0]; xn1 = xr[HID]; xn2 = xr[2 * HID]; xn3 = xr[3 * HID];
    }

    const int buf = it & 1;
    if (it > 0) {
      const unsigned long long* hp =
          hseq + ((((size_t)((it - 1) & 1)) * 2 + d) << 10) + (tid << 1);
      const unsigned target = (unsigned)it;  // producers at it-1 stored seq=it
      unsigned long long q0, q1;
      // staggered double-sample poll: keep a second sample pair in flight
      // while testing the first -> effective sample period ~ RT/2..RT
      unsigned long long qa0 = __hip_atomic_load(hp + 0, __ATOMIC_RELAXED, __HIP_MEMORY_SCOPE_AGENT);
      unsigned long long qa1 = __hip_atomic_load(hp + 1, __ATOMIC_RELAXED, __HIP_MEMORY_SCOPE_AGENT);
      int guard = 1 << 16;
      for (;;) {
        unsigned long long qb0 = __hip_atomic_load(hp + 0, __ATOMIC_RELAXED, __HIP_MEMORY_SCOPE_AGENT);
        unsigned long long qb1 = __hip_atomic_load(hp + 1, __ATOMIC_RELAXED, __HIP_MEMORY_SCOPE_AGENT);
        if ((unsigned)(qa0 >> 32) == target && (unsigned)(qa1 >> 32) == target) {
          q0 = qa0; q1 = qa1; break;
        }
        qa0 = __hip_atomic_load(hp + 0, __ATOMIC_RELAXED, __HIP_MEMORY_SCOPE_AGENT);
        qa1 = __hip_atomic_load(hp + 1, __ATOMIC_RELAXED, __HIP_MEMORY_SCOPE_AGENT);
        if ((unsigned)(qb0 >> 32) == target && (unsigned)(qb1 >> 32) == target) {
          q0 = qb0; q1 = qb1; break;
        }
        if ((guard -= 2) <= 0) { abortf[0] = 1; q0 = qa0; q1 = qa1; break; }
      }
      float2 hv;
      hv.x = __builtin_bit_cast(float, (unsigned)(q0 & 0xffffffffu));
      hv.y = __builtin_bit_cast(float, (unsigned)(q1 & 0xffffffffu));
      *(float2*)&hs[buf][tid << 1] = hv;
    } else {
      *(float2*)&hs[buf][tid << 1] = make_float2(0.f, 0.f);
    }
    __syncthreads();                     // the ONLY barrier per step
    if (abortf[0] != 0) break;           // uniform bail (no deadlock)

    // gate-blocked GEMV: 16 x ds_read_b64, lane-rotated (2-way banks = free),
    // each float2 reused by 4 gates
    float a0 = 0.f, a1 = 0.f, a2 = 0.f, a3 = 0.f;
    const float* hb = &hs[buf][ln << 5];
#pragma unroll
    for (int j = 0; j < 16; ++j) {
      const int bb = (j + ln) & 15;
      const float2 h2 = *(const float2*)&hb[bb << 1];
      a0 += h2.x * w[0][2 * j + 0]; a0 += h2.y * w[0][2 * j + 1];
      a1 += h2.x * w[1][2 * j + 0]; a1 += h2.y * w[1][2 * j + 1];
      a2 += h2.x * w[2][2 * j + 0]; a2 += h2.y * w[2][2 * j + 1];
      a3 += h2.x * w[3][2 * j + 0]; a3 += h2.y * w[3][2 * j + 1];
    }
    // 32-lane butterfly (xor masks 1..16 stay within each 32-lane group)
#pragma unroll
    for (int m = 1; m < 32; m <<= 1) {
      a0 += __shfl_xor(a0, m); a1 += __shfl_xor(a1, m);
      a2 += __shfl_xor(a2, m); a3 += __shfl_xor(a3, m);
    }

    if (ln == 0) {   // leader: all 4 gate sums in-register
      const float gi = a0 + xc0, gf = a1 + xc1, gg = a2 + xc2, go = a3 + xc3;
      const float ii = 1.f / (1.f + expf(-gi));
      const float ff = 1.f / (1.f + expf(-gf));
      const float oo = 1.f / (1.f + expf(-go));
      creg = ff * creg + ii * tanhf(gg);
      const float h = oo * tanhf(creg);
      // packet first: it is on the cross-WG critical path
      const unsigned long long pkt =
          ((unsigned long long)(unsigned)(it + 1) << 32) |
          (unsigned long long)__builtin_bit_cast(unsigned, h);
      __hip_atomic_store(hseq + ((((size_t)(it & 1)) * 2 + d) << 10) + hidx,
                         pkt, __ATOMIC_RELAXED, __HIP_MEMORY_SCOPE_AGENT);
      hout[((size_t)d * T_LEN + t) * HID + hidx] = h;  // plain (for dense)
    }
    xc0 = xn0; xc1 = xn1; xc2 = xn2; xc3 = xn3;   // rotate prefetch
  }
}

// =========================================================================
// 3) dense_w transpose and feats GEMM
// =========================================================================
__global__ void transpose_w(const float* __restrict__ dw, float* __restrict__ WT) {
  const int i = blockIdx.x * 256 + threadIdx.x;
  if (i < KTAG * 2 * HID) {
    const int k = i / (2 * HID), h = i % (2 * HID);
    WT[(size_t)h * KPAD + k] = dw[i];
  }
}

__global__ __launch_bounds__(256, 2) void dense_kernel(
    const float* __restrict__ hout, const float* __restrict__ WT,
    const float* __restrict__ db, float* __restrict__ feats)
{
  __shared__ float hrow[4][2048];
  const int tid = threadIdx.x, w = tid >> 6, l = tid & 63;
  const int t = blockIdx.x * 4 + w;
  const float* hf = hout + (size_t)t * HID;
  const float* hb = hout + ((size_t)T_LEN + t) * HID;
#pragma unroll
  for (int c = 0; c < 4; ++c)
    *(float4*)&hrow[w][c * 256 + l * 4] = *(const float4*)&hf[c * 256 + l * 4];
#pragma unroll
  for (int c = 0; c < 4; ++c)
    *(float4*)&hrow[w][1024 + c * 256 + l * 4] = *(const float4*)&hb[c * 256 + l * 4];
  __syncthreads();
  float acc = (l < KTAG) ? db[l] : 0.f;
#pragma unroll 4
  for (int h = 0; h < 2 * HID; h += 4) {
    const float4 hv = *(const float4*)&hrow[w][h];
    acc += hv.x * WT[(size_t)(h + 0) * KPAD + l];
    acc += hv.y * WT[(size_t)(h + 1) * KPAD + l];
    acc += hv.z * WT[(size_t)(h + 2) * KPAD + l];
    acc += hv.w * WT[(size_t)(h + 3) * KPAD + l];
  }
  if (l < KTAG) feats[(size_t)t * KPAD + l] = acc;
}

// =========================================================================
// 4) Viterbi forward scan — single wave, fully register-resident.
// =========================================================================
__global__ __launch_bounds__(64, 1) void viterbi_fwd(
    const float* __restrict__ feats, const float* __restrict__ trans,
    int* __restrict__ bp, float* __restrict__ out, int* __restrict__ best)
{
  __shared__ float tl[KTAG * 53];
  const int l = threadIdx.x;
  for (int i = l; i < KTAG * KTAG; i += 64) tl[(i / KTAG) * 53 + (i % KTAG)] = trans[i];
  __syncthreads();
  const int lr = (l < KTAG) ? l : (KTAG - 1);
  float tr[KTAG];
#pragma unroll
  for (int p = 0; p < KTAG; ++p) tr[p] = tl[lr * 53 + p];
  const float trE = tl[END_TAG * 53 + lr];

  float fvreg = (l == START_TAG) ? 0.f : -10000.f;
  float ftc = (l < KTAG) ? feats[l] : 0.f;

#pragma unroll 1
  for (int t = 0; t < T_LEN; ++t) {
    float ftn = 0.f;
    if (t + 1 < T_LEN && l < KTAG) ftn = feats[(size_t)(t + 1) * KPAD + l];

    float vm[64]; int va[64];
#pragma unroll
    for (int p = 0; p < KTAG; ++p) {
      const int fb = __builtin_amdgcn_readlane(__builtin_bit_cast(int, fvreg), p);
      vm[p] = tr[p] + __builtin_bit_cast(float, fb);
      va[p] = p;
    }
#pragma unroll
    for (int p = KTAG; p < 64; ++p) { vm[p] = -3.4e38f; va[p] = p; }
#pragma unroll
    for (int w = 32; w >= 1; w >>= 1) {
#pragma unroll
      for (int i = 0; i < w; ++i) {
        if (vm[i + w] > vm[i]) { vm[i] = vm[i + w]; va[i] = va[i + w]; }
      }
    }
    if (l < KTAG) bp[(size_t)t * KPAD + l] = va[0];
    fvreg = vm[0] + ftc;
    ftc = ftn;
  }

  float bv = -3.4e38f; int bi = 1 << 20;
  if (l < KTAG) { bv = fvreg + trE; bi = l; }
#pragma unroll
  for (int m = 1; m < 64; m <<= 1) {
    const float ov = __shfl_xor(bv, m);
    const int   oi = __shfl_xor(bi, m);
    if (ov > bv || (ov == bv && oi < bi)) { bv = ov; bi = oi; }
  }
  if (l == 0) { out[0] = bv; best[0] = bi; }
}

// =========================================================================
// 5) Backtrack via per-chunk map composition (64 chunks of 64 steps)
// =========================================================================
__global__ void bt_chunk(const int* __restrict__ bp, int* __restrict__ mmap) {
  const int c = blockIdx.x, l = threadIdx.x;
  if (l < KTAG) {
    int x = l;
    for (int t = c * 64 + 63; t >= c * 64; --t) x = bp[(size_t)t * KPAD + x];
    mmap[c * 64 + l] = x;
  }
}

__global__ void bt_stitch(const int* __restrict__ mmap, const int* __restrict__ best,
                          int* __restrict__ entry) {
  __shared__ int ml[64 * 64];
  const int tid = threadIdx.x;
  for (int c = 0; c < 64; ++c) ml[c * 64 + tid] = mmap[c * 64 + tid];
  __syncthreads();
  if (tid == 0) {
    int e = best[0];
    for (int c = 63; c >= 0; --c) { entry[c] = e; e = ml[c * 64 + e]; }
  }
}

__global__ void bt_fill(const int* __restrict__ bp, const int* __restrict__ entry,
                        float* __restrict__ out) {
  const int c = blockIdx.x;
  if (threadIdx.x == 0) {
    int x = entry[c];                    // tag at t = c*64+63
    out[1 + c * 64 + 63] = (float)x;
    for (int t = c * 64 + 63; t > c * 64; --t) {
      x = bp[(size_t)t * KPAD + x];
      out[1 + t - 1] = (float)x;
    }
  }
}

// =========================================================================
extern "C" void kernel_launch(void* const* d_in, const int* in_sizes, int n_in,
                              void* d_out, int out_size, void* d_ws, size_t ws_size,
                              hipStream_t stream) {
  (void)in_sizes; (void)n_in; (void)out_size;
  const float* sent  = (const float*)d_in[0];
  const float* wihf  = (const float*)d_in[1];
  const float* whhf  = (const float*)d_in[2];
  const float* bihf  = (const float*)d_in[3];
  const float* bhhf  = (const float*)d_in[4];
  const float* wihb  = (const float*)d_in[5];
  const float* whhb  = (const float*)d_in[6];
  const float* bihb  = (const float*)d_in[7];
  const float* bhhb  = (const float*)d_in[8];
  const float* dw    = (const float*)d_in[9];
  const float* db    = (const float*)d_in[10];
  const float* trans = (const float*)d_in[11];

  if (ws_size < WS_NEEDED) return;
  float* ws    = (float*)d_ws;
  float* xg    = ws + XG_OFF;
  float* hout  = ws + HOUT_OFF;
  float* WT    = ws + WT_OFF;
  float* feats = ws + FEATS_OFF;
  int*   bp    = (int*)(ws + BP_OFF);
  int*   mmap  = (int*)(ws + MMAP_OFF);
  int*   entry = (int*)(ws + ENTRY_OFF);
  int*   best  = (int*)(ws + BEST_OFF);
  unsigned long long* hseq = (unsigned long long*)(ws + HSEQ_OFF);
  float* out = (float*)d_out;

  // zero the 32 KB transport ring: seq targets are >=1, so zeros are inert;
  // keeps every graph replay stale-state-free.
  hipMemsetAsync(hseq, 0, HSEQ_SZ * 4, stream);

  hipLaunchKernelGGL(gemm_xg, dim3(64, 64, 2), dim3(256), 0, stream,
                     sent, wihf, wihb, bihf, bhhf, bihb, bhhb, xg);
  hipLaunchKernelGGL(transpose_w, dim3((KTAG * 2 * HID + 255) / 256), dim3(256), 0, stream,
                     dw, WT);
  {
    const float* a0 = xg; const float* a1 = whhf; const float* a2 = whhb;
    float* a3 = hout; unsigned long long* a4 = hseq;
    void* args[] = { (void*)&a0, (void*)&a1, (void*)&a2, (void*)&a3, (void*)&a4 };
    hipError_t ce = hipLaunchCooperativeKernel((void*)lstm_rec, dim3(128), dim3(512),
                                               args, 0, stream);
    if (ce != hipSuccess) {
      hipLaunchKernelGGL(lstm_rec, dim3(128), dim3(512), 0, stream, a0, a1, a2, a3, a4);
    }
  }
  hipLaunchKernelGGL(dense_kernel, dim3(T_LEN / 4), dim3(256), 0, stream, hout, WT, db, feats);
  hipLaunchKernelGGL(viterbi_fwd, dim3(1), dim3(64), 0, stream, feats, trans, bp, out, best);
  hipLaunchKernelGGL(bt_chunk, dim3(64), dim3(64), 0, stream, bp, mmap);
  hipLaunchKernelGGL(bt_stitch, dim3(1), dim3(64), 0, stream, mmap, best, entry);
  hipLaunchKernelGGL(bt_fill, dim3(64), dim3(64), 0, stream, bp, entry, out);
}